// Round 5
// baseline (253.123 us; speedup 1.0000x reference)
//
#include <hip/hip_runtime.h>
#include <hip/hip_bf16.h>

#define B_SZ 16384
#define I_SZ 256
#define H_SZ 256
#define S_SZ 32

typedef __attribute__((ext_vector_type(8))) short short8;
typedef __attribute__((ext_vector_type(4))) float f32x4;

__device__ __forceinline__ ushort f2b(float f) {
  __hip_bfloat16 h = __float2bfloat16(f);
  return *reinterpret_cast<ushort*>(&h);
}
__device__ __forceinline__ float sgm(float x) { return 1.0f / (1.0f + expf(-x)); }

__device__ __forceinline__ void gll16(const void* g, void* l) {
  __builtin_amdgcn_global_load_lds(
      (const __attribute__((address_space(1))) unsigned*)g,
      (__attribute__((address_space(3))) unsigned*)l, 16, 0, 0);
}

// ============ front kernel: event_pool + all weight prep (block-role split) ==
// blocks [0,4096)        : event/scatter/pool (4 rows each)
// blocks [4096,4104)     : WspT convert-transpose (256x256)
// blocks [4104,4168)     : WcatT k<256 (x part) and k>=512 (h_lstm part)
// blocks [4168,4424)     : Weff = W_sp @ W2 -> bf16 into WcatT k in [256,512)
// block  4424            : bias' = b_ih + b_sp @ W2
__global__ __launch_bounds__(256) void front(
    const float* __restrict__ x_t, const float* __restrict__ h_lstm,
    const float* __restrict__ slots, const int* __restrict__ ptr,
    const float* __restrict__ W_val, const float* __restrict__ b_val,
    const float* __restrict__ W_ev, const float* __restrict__ b_ev,
    const float* __restrict__ pos_emb, const float* __restrict__ slot_w,
    const float* __restrict__ W_sp, const float* __restrict__ W_ih,
    const float* __restrict__ W_hh, const float* __restrict__ b_ih,
    const float* __restrict__ b_sp,
    float* __restrict__ out_slots, float* __restrict__ out_ptr,
    ushort* __restrict__ x_b, ushort* __restrict__ hl_b,
    ushort* __restrict__ pooled_b, ushort* __restrict__ WspT,
    ushort* __restrict__ WcatT, float* __restrict__ biasp) {
  __shared__ float x_sh[4][256];
  __shared__ float w_sh[32];
  const int bid = blockIdx.x;
  const int t = threadIdx.x;

  if (bid < 4096) {
    // ---------------- event / scatter-copy / pool ----------------
    int l = t & 63;
    int w = t >> 6;
    int b = bid * 4 + w;

    // softmax(slot_weights) once per block, in wave 0
    if (t < 32) {
      float v = slot_w[t];
      float m = v;
#pragma unroll
      for (int off = 16; off; off >>= 1) m = fmaxf(m, __shfl_xor(m, off));
      float e = expf(v - m);
      float s2 = e;
#pragma unroll
      for (int off = 16; off; off >>= 1) s2 += __shfl_xor(s2, off);
      w_sh[t] = e / s2;
    }

    float4 x4 = *(const float4*)(x_t + (size_t)b * 256 + l * 4);
    *(float4*)&x_sh[w][l * 4] = x4;
    ushort4 xb = make_ushort4(f2b(x4.x), f2b(x4.y), f2b(x4.z), f2b(x4.w));
    *(ushort4*)&x_b[(size_t)b * 256 + l * 4] = xb;
    float4 hl4 = *(const float4*)(h_lstm + (size_t)b * 256 + l * 4);
    ushort4 hb = make_ushort4(f2b(hl4.x), f2b(hl4.y), f2b(hl4.z), f2b(hl4.w));
    *(ushort4*)&hl_b[(size_t)b * 256 + l * 4] = hb;

    float4 we4 = *(const float4*)(W_ev + l * 4);
    float p = x4.x * we4.x + x4.y * we4.y + x4.z * we4.z + x4.w * we4.w;
    for (int off = 32; off; off >>= 1) p += __shfl_xor(p, off, 64);
    float z = p + b_ev[0];
    bool ev = sgm(z) > 0.85f;
    int pb = ptr[b];

    __syncthreads();

    f32x4 v4 = {0.f, 0.f, 0.f, 0.f};
    if (ev) {
      v4 = *(const f32x4*)(b_val + l * 4);
      for (int k = 0; k < 256; k++) {
        float xv = x_sh[w][k];
        f32x4 wv = *(const f32x4*)(W_val + (size_t)k * 256 + l * 4);
        v4 += xv * wv;
      }
    }

    const f32x4* sl4 = (const f32x4*)slots + (size_t)b * 2048;
    f32x4* os4 = (f32x4*)out_slots + (size_t)b * 2048;
    const f32x4* pe4 = (const f32x4*)pos_emb;
    f32x4 pool = {0.f, 0.f, 0.f, 0.f};
#pragma unroll 8
    for (int s = 0; s < 32; s++) {
      float ws_ = w_sh[s];
      f32x4 tv = __builtin_nontemporal_load(sl4 + s * 64 + l);
      if (ev && s == pb) tv = v4;
      __builtin_nontemporal_store(tv, os4 + s * 64 + l);
      f32x4 pe = pe4[s * 64 + l];
      pool += ws_ * (tv + pe);
    }
    ushort4 pb4 = make_ushort4(f2b(pool[0]), f2b(pool[1]), f2b(pool[2]), f2b(pool[3]));
    *(ushort4*)&pooled_b[(size_t)b * 256 + l * 4] = pb4;

    if (l == 0) out_ptr[b] = (float)(ev ? ((pb + 1) & 31) : pb);

  } else if (bid < 4104) {
    // ---------------- WspT[n][k] = bf16(W_sp[k][n]) ----------------
    for (int e = (bid - 4096) * 256 + t; e < 65536; e += 8 * 256) {
      int n = e >> 8, k = e & 255;
      WspT[e] = f2b(W_sp[k * 256 + n]);
    }
  } else if (bid < 4168) {
    // -------- WcatT rows, k<256 (from W_ih x-part) and k>=512 (W_hh) -------
    for (int e = (bid - 4104) * 256 + t; e < 1024 * 512; e += 64 * 256) {
      int r = e >> 9, kk = e & 511;
      int k = (kk < 256) ? kk : kk + 256;
      int hb = r >> 6, g = (r >> 4) & 3, hl = r & 15;
      int n = g * 256 + hb * 16 + hl;
      float v = (k < 512) ? W_ih[(size_t)k * 1024 + n]
                          : W_hh[(size_t)(k - 512) * 1024 + n];
      WcatT[(size_t)r * 768 + k] = f2b(v);
    }
  } else if (bid < 4424) {
    // -------- Weff[i][n] = sum_m W_sp[i][m] * W_ih[256+m][n]  (fp32) -------
    int i = bid - 4168;
    x_sh[0][t] = W_sp[(size_t)i * 256 + t];
    __syncthreads();
    int n0 = t * 4;
    f32x4 acc = {0.f, 0.f, 0.f, 0.f};
    for (int m = 0; m < 256; m++) {
      float s = x_sh[0][m];
      f32x4 w2 = *(const f32x4*)(W_ih + (size_t)(256 + m) * 1024 + n0);
      acc += s * w2;
    }
#pragma unroll
    for (int d = 0; d < 4; d++) {
      int n = n0 + d;
      int g = n >> 8, rem = n & 255, hb = rem >> 4, hl = rem & 15;
      int r = hb * 64 + g * 16 + hl;
      WcatT[(size_t)r * 768 + 256 + i] = f2b(acc[d]);
    }
  } else {
    // -------- bias'[n] = b_ih[n] + sum_m b_sp[m] * W_ih[256+m][n] ---------
    int n0 = t * 4;
    f32x4 acc = *(const f32x4*)(b_ih + n0);
    for (int m = 0; m < 256; m++) {
      float s = b_sp[m];
      f32x4 w2 = *(const f32x4*)(W_ih + (size_t)(256 + m) * 1024 + n0);
      acc += s * w2;
    }
    *(f32x4*)(biasp + n0) = acc;
  }
}

// ======== merged GEMM: 256x256 tile, BK=64, 4-phase counted-vmcnt pipeline ==
// role gates (id<256):  A=[x|pooled|h_lstm], B=WcatT(1024x768), NT=12,
//                       fused LSTM epilogue.
// role hmem  (id>=256): A=pooled, B=WspT(256x256), NT=4, fp32 h_mem epilogue.
template <int KTOT>
__global__ __launch_bounds__(512) void gemm256_fused(
    const ushort* __restrict__ A0s, const ushort* __restrict__ A1s,
    const ushort* __restrict__ A2s, const ushort* __restrict__ WT,
    const ushort* __restrict__ WspT, const float* __restrict__ bias,
    const float* __restrict__ b_sp, const float* __restrict__ c_lstm,
    float* __restrict__ h_out, float* __restrict__ c_out,
    float* __restrict__ hmem_out) {
  __shared__ ushort Ash[2][2][128][64];
  __shared__ ushort Bsh[2][2][128][64];
  const int tid = threadIdx.x;
  const int l = tid & 63;
  const int wid = tid >> 6;
  const int wm = wid >> 2, wn = wid & 3;
  const int id = blockIdx.x;
  const bool hm = id >= 256;
  int m0, n0, nb = 0;
  if (!hm) {
    const int xcd = id & 7, jj = id >> 3;
    const int mb = xcd * 8 + (jj >> 2);
    nb = jj & 3;
    m0 = mb * 256; n0 = nb * 256;
  } else {
    m0 = (id - 256) * 256; n0 = 0;
  }
  const int nt = hm ? 4 : 12;
  const ushort* Bp = hm ? WspT : WT;
  const int Bstride = hm ? 256 : KTOT;

  auto asel = [&](int kt) {
    return hm ? A1s : (kt < 4 ? A0s : (kt < 8 ? A1s : A2s));
  };

  auto stageA = [&](int bu, int h, int kt) {
    const ushort* s = asel(kt);
    int cb = (kt & 3) * 64;
#pragma unroll
    for (int ld = 0; ld < 2; ld++) {
      int seg = ld * 512 + tid;
      int row = seg >> 3, C = seg & 7;
      int Cs = C ^ (row & 7);
      gll16(s + (size_t)(m0 + h * 128 + row) * 256 + cb + Cs * 8,
            &Ash[bu][h][0][0] + seg * 8);
    }
  };
  auto stageB = [&](int bu, int h, int kt) {
    int cb = kt * 64;
#pragma unroll
    for (int ld = 0; ld < 2; ld++) {
      int seg = ld * 512 + tid;
      int row = seg >> 3, C = seg & 7;
      int Cs = C ^ (row & 7);
      gll16(Bp + (size_t)(n0 + h * 128 + row) * Bstride + cb + Cs * 8,
            &Bsh[bu][h][0][0] + seg * 8);
    }
  };

  f32x4 acc[8][4] = {};

  stageB(0, 0, 0); stageB(0, 1, 0);
  stageA(0, 0, 0); stageA(0, 1, 0);
  stageB(1, 0, 1); stageB(1, 1, 1);

  for (int t = 0; t < nt; t++) {
    const int c = t & 1;
    const ushort* Abase = &Ash[c][wm][0][0];
    const ushort* Bbase = &Bsh[c][wn >> 1][0][0];

    if (t < nt - 1) asm volatile("s_waitcnt vmcnt(4)" ::: "memory");
    else            asm volatile("s_waitcnt vmcnt(0)" ::: "memory");
    asm volatile("s_barrier" ::: "memory");

    short8 bfr[4][2];
#pragma unroll
    for (int nf = 0; nf < 4; nf++)
#pragma unroll
      for (int kk = 0; kk < 2; kk++) {
        int r = (wn & 1) * 64 + nf * 16 + (l & 15);
        int C = (kk * 4 + (l >> 4)) ^ (l & 7);
        bfr[nf][kk] = *(const short8*)(Bbase + r * 64 + C * 8);
      }
    short8 af[2][2];
#pragma unroll
    for (int q = 0; q < 2; q++)
#pragma unroll
      for (int kk = 0; kk < 2; kk++) {
        int r = (0 * 2 + q) * 16 + (l & 15);
        int C = (kk * 4 + (l >> 4)) ^ (l & 7);
        af[q][kk] = *(const short8*)(Abase + r * 64 + C * 8);
      }
    if (t + 1 < nt) stageA(c ^ 1, 0, t + 1);
    __builtin_amdgcn_s_setprio(1);
#pragma unroll
    for (int q = 0; q < 2; q++)
#pragma unroll
      for (int nf = 0; nf < 4; nf++)
#pragma unroll
        for (int kk = 0; kk < 2; kk++)
          acc[q][nf] = __builtin_amdgcn_mfma_f32_16x16x32_bf16(
              af[q][kk], bfr[nf][kk], acc[q][nf], 0, 0, 0);
    __builtin_amdgcn_s_setprio(0);

#pragma unroll
    for (int p = 1; p < 4; p++) {
      asm volatile("s_barrier" ::: "memory");
#pragma unroll
      for (int q = 0; q < 2; q++)
#pragma unroll
        for (int kk = 0; kk < 2; kk++) {
          int r = (p * 2 + q) * 16 + (l & 15);
          int C = (kk * 4 + (l >> 4)) ^ (l & 7);
          af[q][kk] = *(const short8*)(Abase + r * 64 + C * 8);
        }
      if (p == 1) {
        if (t + 1 < nt) stageA(c ^ 1, 1, t + 1);
        if (t + 2 < nt) stageB(c, 0, t + 2);
      } else if (p == 2) {
        if (t + 2 < nt) stageB(c, 1, t + 2);
      }
      __builtin_amdgcn_s_setprio(1);
#pragma unroll
      for (int q = 0; q < 2; q++)
#pragma unroll
        for (int nf = 0; nf < 4; nf++)
#pragma unroll
          for (int kk = 0; kk < 2; kk++)
            acc[p * 2 + q][nf] = __builtin_amdgcn_mfma_f32_16x16x32_bf16(
                af[q][kk], bfr[nf][kk], acc[p * 2 + q][nf], 0, 0, 0);
      __builtin_amdgcn_s_setprio(0);
    }
  }

  if (!hm) {
    int h = (nb * 4 + wn) * 16 + (l & 15);
    float bi = bias[h], bf_ = bias[256 + h], bg = bias[512 + h], bo = bias[768 + h];
#pragma unroll
    for (int mf = 0; mf < 8; mf++)
#pragma unroll
      for (int r = 0; r < 4; r++) {
        int row = m0 + wm * 128 + mf * 16 + (l >> 4) * 4 + r;
        float ig = acc[mf][0][r] + bi;
        float fg = acc[mf][1][r] + bf_;
        float gt = acc[mf][2][r] + bg;
        float og = acc[mf][3][r] + bo;
        float cc = c_lstm[(size_t)row * 256 + h];
        float cn = sgm(fg) * cc + sgm(ig) * tanhf(gt);
        float hn = sgm(og) * tanhf(cn);
        c_out[(size_t)row * 256 + h] = cn;
        h_out[(size_t)row * 256 + h] = hn;
      }
  } else {
#pragma unroll
    for (int nf = 0; nf < 4; nf++) {
      int col = wn * 64 + nf * 16 + (l & 15);
      float bb = b_sp[col];
#pragma unroll
      for (int mf = 0; mf < 8; mf++)
#pragma unroll
        for (int r = 0; r < 4; r++) {
          int row = m0 + wm * 128 + mf * 16 + (l >> 4) * 4 + r;
          hmem_out[(size_t)row * 256 + col] = acc[mf][nf][r] + bb;
        }
    }
  }
}

extern "C" void kernel_launch(void* const* d_in, const int* in_sizes, int n_in,
                              void* d_out, int out_size, void* d_ws, size_t ws_size,
                              hipStream_t stream) {
  const float* x_t    = (const float*)d_in[0];
  const float* h_lstm = (const float*)d_in[1];
  const float* c_lstm = (const float*)d_in[2];
  const float* slots  = (const float*)d_in[4];
  const int*   ptr    = (const int*)d_in[5];
  const float* W_val  = (const float*)d_in[6];
  const float* b_val  = (const float*)d_in[7];
  const float* W_ev   = (const float*)d_in[8];
  const float* b_ev   = (const float*)d_in[9];
  const float* pos_emb = (const float*)d_in[10];
  const float* slot_w  = (const float*)d_in[11];
  const float* W_sp   = (const float*)d_in[12];
  const float* b_sp   = (const float*)d_in[13];
  const float* W_ih   = (const float*)d_in[14];
  const float* b_ih   = (const float*)d_in[15];
  const float* W_hh   = (const float*)d_in[16];

  float* out = (float*)d_out;
  const size_t BH = (size_t)B_SZ * H_SZ;
  float* out_h    = out;
  float* out_c    = out + BH;
  float* out_hmem = out + 2 * BH;
  float* out_slots = out + 3 * BH;
  float* out_ptr   = out + 3 * BH + (size_t)B_SZ * S_SZ * I_SZ;

  char* ws = (char*)d_ws;
  ushort* x_b      = (ushort*)(ws);                        // 8 MB
  ushort* hl_b     = (ushort*)(ws + 8388608);              // 8 MB
  ushort* pooled_b = (ushort*)(ws + 16777216);             // 8 MB
  ushort* WspT     = (ushort*)(ws + 25165824);             // 128 KB
  ushort* WcatT    = (ushort*)(ws + 25296896);             // 1.5 MB
  float*  biasp    = (float*)(ws + 26869760);              // 4 KB

  front<<<4425, 256, 0, stream>>>(
      x_t, h_lstm, slots, ptr, W_val, b_val, W_ev, b_ev, pos_emb, slot_w,
      W_sp, W_ih, W_hh, b_ih, b_sp,
      out_slots, out_ptr, x_b, hl_b, pooled_b, WspT, WcatT, biasp);

  // gates (fused LSTM) + h_mem GEMM in one launch (block-role split)
  gemm256_fused<768><<<320, 512, 0, stream>>>(
      x_b, pooled_b, hl_b, WcatT, WspT, biasp, b_sp, c_lstm,
      out_h, out_c, out_hmem);
}

// Round 6
// 250.202 us; speedup vs baseline: 1.0117x; 1.0117x over previous
//
#include <hip/hip_runtime.h>
#include <hip/hip_bf16.h>

#define B_SZ 16384
#define I_SZ 256
#define H_SZ 256
#define S_SZ 32

typedef __attribute__((ext_vector_type(8))) short short8;
typedef __attribute__((ext_vector_type(4))) float f32x4;

__device__ __forceinline__ ushort f2b(float f) {
  __hip_bfloat16 h = __float2bfloat16(f);
  return *reinterpret_cast<ushort*>(&h);
}
__device__ __forceinline__ float sgm(float x) { return 1.0f / (1.0f + expf(-x)); }

__device__ __forceinline__ void gll16(const void* g, void* l) {
  __builtin_amdgcn_global_load_lds(
      (const __attribute__((address_space(1))) unsigned*)g,
      (__attribute__((address_space(3))) unsigned*)l, 16, 0, 0);
}

// ============ front kernel: event_pool + all weight prep (block-role split) ==
// blocks [0,4096)        : event/scatter/pool (4 rows each)
// blocks [4096,4104)     : WspT convert-transpose (256x256)
// blocks [4104,4168)     : WcatT k<256 (x part) and k>=512 (h_lstm part)
// blocks [4168,4424)     : Weff = W_sp @ W2 -> bf16 into WcatT k in [256,512)
// block  4424            : bias' = b_ih + b_sp @ W2
__global__ __launch_bounds__(256) void front(
    const float* __restrict__ x_t, const float* __restrict__ h_lstm,
    const float* __restrict__ slots, const int* __restrict__ ptr,
    const float* __restrict__ W_val, const float* __restrict__ b_val,
    const float* __restrict__ W_ev, const float* __restrict__ b_ev,
    const float* __restrict__ pos_emb, const float* __restrict__ slot_w,
    const float* __restrict__ W_sp, const float* __restrict__ W_ih,
    const float* __restrict__ W_hh, const float* __restrict__ b_ih,
    const float* __restrict__ b_sp,
    float* __restrict__ out_slots, float* __restrict__ out_ptr,
    ushort* __restrict__ x_b, ushort* __restrict__ hl_b,
    ushort* __restrict__ pooled_b, ushort* __restrict__ WspT,
    ushort* __restrict__ WcatT, float* __restrict__ biasp) {
  __shared__ float x_sh[4][256];
  __shared__ float w_sh[32];
  __shared__ float pe_sh[256];
  const int bid = blockIdx.x;
  const int t = threadIdx.x;

  if (bid < 4096) {
    // ---------------- event / scatter-copy / pool ----------------
    int l = t & 63;
    int w = t >> 6;
    int b = bid * 4 + w;

    // softmax(slot_weights) once per block, in wave 0
    if (t < 32) {
      float v = slot_w[t];
      float m = v;
#pragma unroll
      for (int off = 16; off; off >>= 1) m = fmaxf(m, __shfl_xor(m, off));
      float e = expf(v - m);
      float s2 = e;
#pragma unroll
      for (int off = 16; off; off >>= 1) s2 += __shfl_xor(s2, off);
      w_sh[t] = e / s2;
    }

    float4 x4 = *(const float4*)(x_t + (size_t)b * 256 + l * 4);
    *(float4*)&x_sh[w][l * 4] = x4;
    ushort4 xb = make_ushort4(f2b(x4.x), f2b(x4.y), f2b(x4.z), f2b(x4.w));
    *(ushort4*)&x_b[(size_t)b * 256 + l * 4] = xb;
    float4 hl4 = *(const float4*)(h_lstm + (size_t)b * 256 + l * 4);
    ushort4 hb = make_ushort4(f2b(hl4.x), f2b(hl4.y), f2b(hl4.z), f2b(hl4.w));
    *(ushort4*)&hl_b[(size_t)b * 256 + l * 4] = hb;

    float4 we4 = *(const float4*)(W_ev + l * 4);
    float p = x4.x * we4.x + x4.y * we4.y + x4.z * we4.z + x4.w * we4.w;
    for (int off = 32; off; off >>= 1) p += __shfl_xor(p, off, 64);
    float z = p + b_ev[0];
    bool ev = sgm(z) > 0.85f;
    int pb = ptr[b];
    if (l == 0) out_ptr[b] = (float)(ev ? ((pb + 1) & 31) : pb);

    __syncthreads();  // w_sh + x_sh ready

    // PE[i] = sum_s w_s * pos_emb[s][i]  — constant over batch rows;
    // computed once per block (cuts pos_emb L2 traffic 4x, strips hot loop)
    {
      float accp = 0.f;
#pragma unroll 8
      for (int s = 0; s < 32; s++) accp += w_sh[s] * pos_emb[s * 256 + t];
      pe_sh[t] = accp;
    }

    f32x4 v4 = {0.f, 0.f, 0.f, 0.f};
    if (ev) {
      v4 = *(const f32x4*)(b_val + l * 4);
      for (int k = 0; k < 256; k++) {
        float xv = x_sh[w][k];
        f32x4 wv = *(const f32x4*)(W_val + (size_t)k * 256 + l * 4);
        v4 += xv * wv;
      }
    }

    __syncthreads();  // pe_sh ready
    f32x4 pev = *(const f32x4*)&pe_sh[l * 4];

    const f32x4* sl4 = (const f32x4*)slots + (size_t)b * 2048;
    f32x4* os4 = (f32x4*)out_slots + (size_t)b * 2048;
    f32x4 pool = {0.f, 0.f, 0.f, 0.f};
#pragma unroll 8
    for (int s = 0; s < 32; s++) {
      f32x4 tv = __builtin_nontemporal_load(sl4 + s * 64 + l);
      if (ev && s == pb) tv = v4;
      __builtin_nontemporal_store(tv, os4 + s * 64 + l);
      pool += w_sh[s] * tv;
    }
    pool += pev;
    ushort4 pb4 = make_ushort4(f2b(pool[0]), f2b(pool[1]), f2b(pool[2]), f2b(pool[3]));
    *(ushort4*)&pooled_b[(size_t)b * 256 + l * 4] = pb4;

  } else if (bid < 4104) {
    // ---------------- WspT[n][k] = bf16(W_sp[k][n]) ----------------
    for (int e = (bid - 4096) * 256 + t; e < 65536; e += 8 * 256) {
      int n = e >> 8, k = e & 255;
      WspT[e] = f2b(W_sp[k * 256 + n]);
    }
  } else if (bid < 4168) {
    // -------- WcatT rows, k<256 (from W_ih x-part) and k>=512 (W_hh) -------
    for (int e = (bid - 4104) * 256 + t; e < 1024 * 512; e += 64 * 256) {
      int r = e >> 9, kk = e & 511;
      int k = (kk < 256) ? kk : kk + 256;
      int hb = r >> 6, g = (r >> 4) & 3, hl = r & 15;
      int n = g * 256 + hb * 16 + hl;
      float v = (k < 512) ? W_ih[(size_t)k * 1024 + n]
                          : W_hh[(size_t)(k - 512) * 1024 + n];
      WcatT[(size_t)r * 768 + k] = f2b(v);
    }
  } else if (bid < 4424) {
    // -------- Weff[i][n] = sum_m W_sp[i][m] * W_ih[256+m][n]  (fp32) -------
    int i = bid - 4168;
    x_sh[0][t] = W_sp[(size_t)i * 256 + t];
    __syncthreads();
    int n0 = t * 4;
    f32x4 acc = {0.f, 0.f, 0.f, 0.f};
    for (int m = 0; m < 256; m++) {
      float s = x_sh[0][m];
      f32x4 w2 = *(const f32x4*)(W_ih + (size_t)(256 + m) * 1024 + n0);
      acc += s * w2;
    }
#pragma unroll
    for (int d = 0; d < 4; d++) {
      int n = n0 + d;
      int g = n >> 8, rem = n & 255, hb = rem >> 4, hl = rem & 15;
      int r = hb * 64 + g * 16 + hl;
      WcatT[(size_t)r * 768 + 256 + i] = f2b(acc[d]);
    }
  } else {
    // -------- bias'[n] = b_ih[n] + sum_m b_sp[m] * W_ih[256+m][n] ---------
    int n0 = t * 4;
    f32x4 acc = *(const f32x4*)(b_ih + n0);
    for (int m = 0; m < 256; m++) {
      float s = b_sp[m];
      f32x4 w2 = *(const f32x4*)(W_ih + (size_t)(256 + m) * 1024 + n0);
      acc += s * w2;
    }
    *(f32x4*)(biasp + n0) = acc;
  }
}

// ---------------- h_mem output GEMM (fp32 out only): 128^2 tile -------------
__global__ __launch_bounds__(256) void gemm_hmem(
    const ushort* __restrict__ A0, const ushort* __restrict__ WT,
    const float* __restrict__ bias, float* __restrict__ out_f32) {
  int l = threadIdx.x & 63;
  int wid = threadIdx.x >> 6;
  int wm = wid >> 1, wn = wid & 1;
  int m0 = blockIdx.x * 128;
  int n0 = blockIdx.y * 128;
  __shared__ ushort Ash[128 * 32];
  __shared__ ushort Bsh[128 * 32];

  f32x4 acc[4][4] = {};

  for (int k0 = 0; k0 < 256; k0 += 32) {
#pragma unroll
    for (int i = 0; i < 2; i++) {
      int seg = i * 256 + threadIdx.x;
      int row = seg >> 2, cb = (seg & 3) * 8;
      gll16(A0 + (size_t)(m0 + row) * 256 + k0 + cb, Ash + seg * 8);
    }
#pragma unroll
    for (int i = 0; i < 2; i++) {
      int seg = i * 256 + threadIdx.x;
      int row = seg >> 2, cb = (seg & 3) * 8;
      gll16(WT + (size_t)(n0 + row) * 256 + k0 + cb, Bsh + seg * 8);
    }
    __syncthreads();

    short8 af[4], bfr[4];
#pragma unroll
    for (int m = 0; m < 4; m++)
      af[m] = *(const short8*)&Ash[(wm * 64 + m * 16 + (l & 15)) * 32 + (l >> 4) * 8];
#pragma unroll
    for (int n = 0; n < 4; n++)
      bfr[n] = *(const short8*)&Bsh[(wn * 64 + n * 16 + (l & 15)) * 32 + (l >> 4) * 8];
#pragma unroll
    for (int m = 0; m < 4; m++)
#pragma unroll
      for (int n = 0; n < 4; n++)
        acc[m][n] = __builtin_amdgcn_mfma_f32_16x16x32_bf16(af[m], bfr[n], acc[m][n], 0, 0, 0);
    __syncthreads();
  }

#pragma unroll
  for (int m = 0; m < 4; m++)
#pragma unroll
    for (int n = 0; n < 4; n++)
#pragma unroll
      for (int r = 0; r < 4; r++) {
        int row = m0 + wm * 64 + m * 16 + (l >> 4) * 4 + r;
        int col = n0 + wn * 64 + n * 16 + (l & 15);
        out_f32[(size_t)row * 256 + col] = acc[m][n][r] + bias[col];
      }
}

// ------- gates GEMM, 256x256 tile, BK=64, 4-phase counted-vmcnt pipeline ----
// A = [x | pooled | h_lstm], B = WcatT (x | Weff | h_lstm segments,
// gate-interleaved rows). Fused LSTM epilogue.
template <int KTOT>
__global__ __launch_bounds__(512) void gemm256_lstm(
    const ushort* __restrict__ A0s, const ushort* __restrict__ A1s,
    const ushort* __restrict__ A2s, const ushort* __restrict__ WT,
    const float* __restrict__ bias, const float* __restrict__ c_lstm,
    float* __restrict__ h_out, float* __restrict__ c_out) {
  constexpr int NT = KTOT / 64;  // 12
  __shared__ ushort Ash[2][2][128][64];
  __shared__ ushort Bsh[2][2][128][64];
  const int tid = threadIdx.x;
  const int l = tid & 63;
  const int wid = tid >> 6;
  const int wm = wid >> 2, wn = wid & 3;
  const int id = blockIdx.x;
  const int xcd = id & 7, jj = id >> 3;
  const int mb = xcd * 8 + (jj >> 2), nb = jj & 3;
  const int m0 = mb * 256, n0 = nb * 256;

  auto asel = [&](int kt) { return kt < 4 ? A0s : (kt < 8 ? A1s : A2s); };

  auto stageA = [&](int bu, int h, int kt) {
    const ushort* s = asel(kt);
    int cb = (kt & 3) * 64;
#pragma unroll
    for (int ld = 0; ld < 2; ld++) {
      int seg = ld * 512 + tid;
      int row = seg >> 3, C = seg & 7;
      int Cs = C ^ (row & 7);
      gll16(s + (size_t)(m0 + h * 128 + row) * 256 + cb + Cs * 8,
            &Ash[bu][h][0][0] + seg * 8);
    }
  };
  auto stageB = [&](int bu, int h, int kt) {
    int cb = kt * 64;
#pragma unroll
    for (int ld = 0; ld < 2; ld++) {
      int seg = ld * 512 + tid;
      int row = seg >> 3, C = seg & 7;
      int Cs = C ^ (row & 7);
      gll16(WT + (size_t)(n0 + h * 128 + row) * KTOT + cb + Cs * 8,
            &Bsh[bu][h][0][0] + seg * 8);
    }
  };

  f32x4 acc[8][4] = {};

  stageB(0, 0, 0); stageB(0, 1, 0);
  stageA(0, 0, 0); stageA(0, 1, 0);
  stageB(1, 0, 1); stageB(1, 1, 1);

  for (int t = 0; t < NT; t++) {
    const int c = t & 1;
    const ushort* Abase = &Ash[c][wm][0][0];
    const ushort* Bbase = &Bsh[c][wn >> 1][0][0];

    if (t < NT - 1) asm volatile("s_waitcnt vmcnt(4)" ::: "memory");
    else            asm volatile("s_waitcnt vmcnt(0)" ::: "memory");
    asm volatile("s_barrier" ::: "memory");

    short8 bfr[4][2];
#pragma unroll
    for (int nf = 0; nf < 4; nf++)
#pragma unroll
      for (int kk = 0; kk < 2; kk++) {
        int r = (wn & 1) * 64 + nf * 16 + (l & 15);
        int C = (kk * 4 + (l >> 4)) ^ (l & 7);
        bfr[nf][kk] = *(const short8*)(Bbase + r * 64 + C * 8);
      }
    short8 af[2][2];
#pragma unroll
    for (int q = 0; q < 2; q++)
#pragma unroll
      for (int kk = 0; kk < 2; kk++) {
        int r = (0 * 2 + q) * 16 + (l & 15);
        int C = (kk * 4 + (l >> 4)) ^ (l & 7);
        af[q][kk] = *(const short8*)(Abase + r * 64 + C * 8);
      }
    if (t + 1 < NT) stageA(c ^ 1, 0, t + 1);
    __builtin_amdgcn_s_setprio(1);
#pragma unroll
    for (int q = 0; q < 2; q++)
#pragma unroll
      for (int nf = 0; nf < 4; nf++)
#pragma unroll
        for (int kk = 0; kk < 2; kk++)
          acc[q][nf] = __builtin_amdgcn_mfma_f32_16x16x32_bf16(
              af[q][kk], bfr[nf][kk], acc[q][nf], 0, 0, 0);
    __builtin_amdgcn_s_setprio(0);

#pragma unroll
    for (int p = 1; p < 4; p++) {
      asm volatile("s_barrier" ::: "memory");
#pragma unroll
      for (int q = 0; q < 2; q++)
#pragma unroll
        for (int kk = 0; kk < 2; kk++) {
          int r = (p * 2 + q) * 16 + (l & 15);
          int C = (kk * 4 + (l >> 4)) ^ (l & 7);
          af[q][kk] = *(const short8*)(Abase + r * 64 + C * 8);
        }
      if (p == 1) {
        if (t + 1 < NT) stageA(c ^ 1, 1, t + 1);
        if (t + 2 < NT) stageB(c, 0, t + 2);
      } else if (p == 2) {
        if (t + 2 < NT) stageB(c, 1, t + 2);
      }
      __builtin_amdgcn_s_setprio(1);
#pragma unroll
      for (int q = 0; q < 2; q++)
#pragma unroll
        for (int nf = 0; nf < 4; nf++)
#pragma unroll
          for (int kk = 0; kk < 2; kk++)
            acc[p * 2 + q][nf] = __builtin_amdgcn_mfma_f32_16x16x32_bf16(
                af[q][kk], bfr[nf][kk], acc[p * 2 + q][nf], 0, 0, 0);
      __builtin_amdgcn_s_setprio(0);
    }
  }

  int h = (nb * 4 + wn) * 16 + (l & 15);
  float bi = bias[h], bf_ = bias[256 + h], bg = bias[512 + h], bo = bias[768 + h];
#pragma unroll
  for (int mf = 0; mf < 8; mf++)
#pragma unroll
    for (int r = 0; r < 4; r++) {
      int row = m0 + wm * 128 + mf * 16 + (l >> 4) * 4 + r;
      float ig = acc[mf][0][r] + bi;
      float fg = acc[mf][1][r] + bf_;
      float gt = acc[mf][2][r] + bg;
      float og = acc[mf][3][r] + bo;
      float cc = c_lstm[(size_t)row * 256 + h];
      float cn = sgm(fg) * cc + sgm(ig) * tanhf(gt);
      float hn = sgm(og) * tanhf(cn);
      c_out[(size_t)row * 256 + h] = cn;
      h_out[(size_t)row * 256 + h] = hn;
    }
}

extern "C" void kernel_launch(void* const* d_in, const int* in_sizes, int n_in,
                              void* d_out, int out_size, void* d_ws, size_t ws_size,
                              hipStream_t stream) {
  const float* x_t    = (const float*)d_in[0];
  const float* h_lstm = (const float*)d_in[1];
  const float* c_lstm = (const float*)d_in[2];
  const float* slots  = (const float*)d_in[4];
  const int*   ptr    = (const int*)d_in[5];
  const float* W_val  = (const float*)d_in[6];
  const float* b_val  = (const float*)d_in[7];
  const float* W_ev   = (const float*)d_in[8];
  const float* b_ev   = (const float*)d_in[9];
  const float* pos_emb = (const float*)d_in[10];
  const float* slot_w  = (const float*)d_in[11];
  const float* W_sp   = (const float*)d_in[12];
  const float* b_sp   = (const float*)d_in[13];
  const float* W_ih   = (const float*)d_in[14];
  const float* b_ih   = (const float*)d_in[15];
  const float* W_hh   = (const float*)d_in[16];

  float* out = (float*)d_out;
  const size_t BH = (size_t)B_SZ * H_SZ;
  float* out_h    = out;
  float* out_c    = out + BH;
  float* out_hmem = out + 2 * BH;
  float* out_slots = out + 3 * BH;
  float* out_ptr   = out + 3 * BH + (size_t)B_SZ * S_SZ * I_SZ;

  char* ws = (char*)d_ws;
  ushort* x_b      = (ushort*)(ws);                        // 8 MB
  ushort* hl_b     = (ushort*)(ws + 8388608);              // 8 MB
  ushort* pooled_b = (ushort*)(ws + 16777216);             // 8 MB
  ushort* WspT     = (ushort*)(ws + 25165824);             // 128 KB
  ushort* WcatT    = (ushort*)(ws + 25296896);             // 1.5 MB
  float*  biasp    = (float*)(ws + 26869760);              // 4 KB

  front<<<4425, 256, 0, stream>>>(
      x_t, h_lstm, slots, ptr, W_val, b_val, W_ev, b_ev, pos_emb, slot_w,
      W_sp, W_ih, W_hh, b_ih, b_sp,
      out_slots, out_ptr, x_b, hl_b, pooled_b, WspT, WcatT, biasp);

  // gates = [x | pooled | h_lstm] @ WcatT + bias', fused LSTM
  gemm256_lstm<768><<<256, 512, 0, stream>>>(
      x_b, pooled_b, hl_b, WcatT, biasp, c_lstm, out_h, out_c);

  // h_mem = pooled @ W_sp + b_sp  (fp32 output only)
  gemm_hmem<<<dim3(128, 2), 256, 0, stream>>>(
      pooled_b, WspT, b_sp, out_hmem);
}